// Round 1
// baseline (951.311 us; speedup 1.0000x reference)
//
#include <hip/hip_runtime.h>

#define NR 131072
#define FEA 512
#define MEM 320
#define NCLS 10
#define SHRK 0.0025f
#define EPSV 1e-12f

typedef short bh8 __attribute__((ext_vector_type(8)));
typedef float f4  __attribute__((ext_vector_type(4)));

__device__ inline unsigned short f2b(float f) {
    union { float f; unsigned int u; } c; c.f = f;
    unsigned int u = c.u;
    u += 0x7FFFu + ((u >> 16) & 1u);
    return (unsigned short)(u >> 16);
}

__device__ inline float sigm(float x) { return 1.f / (1.f + __expf(-x)); }

// ---------- P1: cast W to bf16 (row-major) + transposed ----------
__global__ void cast_w(const float* __restrict__ W, unsigned short* __restrict__ Wb,
                       unsigned short* __restrict__ Wt) {
    int idx = blockIdx.x * 256 + threadIdx.x;
    if (idx >= MEM * FEA) return;
    int n = idx >> 9, k = idx & 511;
    unsigned short b = f2b(W[idx]);
    Wb[idx] = b;
    Wt[k * MEM + n] = b;
}

// ---------- P2: exact fp32 sem_att [10][512] ----------
__global__ void sem_kernel(const float* __restrict__ W, const float* __restrict__ wp,
                           const float* __restrict__ bp, const float* __restrict__ wi,
                           const float* __restrict__ bi, float* __restrict__ sem_ws,
                           float* __restrict__ out2) {
    int c = blockIdx.x * 64 + threadIdx.x;  // 0..511
    float pa[8];
    for (int l = 0; l < NCLS; ++l) {
#pragma unroll
        for (int t = 0; t < 8; ++t) {
            int n = l * 8 + t;
            const float* wb = W + n * 2048 + c * 4;
            float wv[4] = {wb[0], wb[1], wb[2], wb[3]};
            float s = 0.f;
#pragma unroll
            for (int q = 0; q < 4; ++q) {
                float z = bp[q] + wp[q*4+0]*wv[0] + wp[q*4+1]*wv[1]
                                + wp[q*4+2]*wv[2] + wp[q*4+3]*wv[3];
                s += sigm(z) * wv[q];
            }
            pa[t] = 0.25f * s;
        }
        float s2 = 0.f;
#pragma unroll
        for (int q = 0; q < 8; ++q) {
            float z = bi[q];
#pragma unroll
            for (int t = 0; t < 8; ++t) z += wi[q*8+t] * pa[t];
            s2 += sigm(z) * pa[q];
        }
        float v = 0.125f * s2;
        sem_ws[l * FEA + c] = v;
        out2[l * FEA + c]   = v;
    }
}

// ---------- main fused kernel: 64 rows / block, 4 waves ----------
__global__ __launch_bounds__(256, 2) void fused_kernel(
    const float* __restrict__ x, const unsigned short* __restrict__ Wb,
    const unsigned short* __restrict__ Wt, const float* __restrict__ sem_g,
    float* __restrict__ out0, float* __restrict__ out1, float* __restrict__ out3)
{
    __shared__ unsigned short big[20992];   // att [64][328] bf16, later semT [512][40]
    __shared__ unsigned short slab[6400];   // staging [160][40], later att2 [64][40]

    const int tid  = threadIdx.x;
    const int wave = tid >> 6, lane = tid & 63;
    const int quad = lane >> 4, l16 = lane & 15;
    const int m0 = wave * 16;
    const long rowbase = (long)blockIdx.x * 64;
    const float* xrow = x + (rowbase + m0 + l16) * FEA;

    // ================= GEMM1: logits = x @ W^T  (M=64,N=320,K=512) =================
    f4 acc[20];
#pragma unroll
    for (int t = 0; t < 20; ++t) acc[t] = (f4){0.f, 0.f, 0.f, 0.f};

    for (int s = 0; s < 16; ++s) {
        const float* ap = xrow + s * 32 + quad * 8;
        float4 a0 = *(const float4*)ap;
        float4 a1 = *(const float4*)(ap + 4);
        bh8 af;
        af[0]=(short)f2b(a0.x); af[1]=(short)f2b(a0.y); af[2]=(short)f2b(a0.z); af[3]=(short)f2b(a0.w);
        af[4]=(short)f2b(a1.x); af[5]=(short)f2b(a1.y); af[6]=(short)f2b(a1.z); af[7]=(short)f2b(a1.w);
#pragma unroll
        for (int h = 0; h < 2; ++h) {
            __syncthreads();
            for (int i = 0; i < 3; ++i) {
                int u = i * 256 + tid;
                if (u < 640) {
                    int row = u >> 2, off = u & 3;
                    *(bh8*)&slab[row * 40 + off * 8] =
                        *(const bh8*)&Wb[(h * 160 + row) * FEA + s * 32 + off * 8];
                }
            }
            __syncthreads();
#pragma unroll
            for (int t = 0; t < 10; ++t) {
                bh8 bf = *(const bh8*)&slab[(t * 16 + l16) * 40 + quad * 8];
                acc[h*10+t] = __builtin_amdgcn_mfma_f32_16x16x32_bf16(af, bf, acc[h*10+t], 0, 0, 0);
            }
        }
    }

    // ============ softmax(320) + hard_shrink + L1 norm, rows = quad*4+r ============
    float mx[4], sm[4], s2[4];
#pragma unroll
    for (int r = 0; r < 4; ++r) mx[r] = acc[0][r];
#pragma unroll
    for (int t = 1; t < 20; ++t)
#pragma unroll
        for (int r = 0; r < 4; ++r) mx[r] = fmaxf(mx[r], acc[t][r]);
    for (int d = 1; d < 16; d <<= 1)
#pragma unroll
        for (int r = 0; r < 4; ++r) mx[r] = fmaxf(mx[r], __shfl_xor(mx[r], d));
#pragma unroll
    for (int r = 0; r < 4; ++r) sm[r] = 0.f;
#pragma unroll
    for (int t = 0; t < 20; ++t)
#pragma unroll
        for (int r = 0; r < 4; ++r) { float e = __expf(acc[t][r] - mx[r]); acc[t][r] = e; sm[r] += e; }
    for (int d = 1; d < 16; d <<= 1)
#pragma unroll
        for (int r = 0; r < 4; ++r) sm[r] += __shfl_xor(sm[r], d);
#pragma unroll
    for (int r = 0; r < 4; ++r) { s2[r] = 0.f; sm[r] = 1.f / sm[r]; }
#pragma unroll
    for (int t = 0; t < 20; ++t)
#pragma unroll
        for (int r = 0; r < 4; ++r) {
            float p  = acc[t][r] * sm[r];
            float hs = (p > SHRK) ? ((p - SHRK) * p / (p - SHRK + EPSV)) : 0.f;
            acc[t][r] = hs; s2[r] += hs;
        }
    for (int d = 1; d < 16; d <<= 1)
#pragma unroll
        for (int r = 0; r < 4; ++r) s2[r] += __shfl_xor(s2[r], d);
#pragma unroll
    for (int r = 0; r < 4; ++r) s2[r] = 1.f / fmaxf(s2[r], EPSV);
#pragma unroll
    for (int t = 0; t < 20; ++t)
#pragma unroll
        for (int r = 0; r < 4; ++r)
            big[(m0 + quad * 4 + r) * 328 + t * 16 + l16] = f2b(acc[t][r] * s2[r]);
    __syncthreads();  // att fully written before any A-frag read

    // ================= GEMM2: output_part = att @ W  (M=64,N=512,K=320) =============
#pragma unroll 1
    for (int pass = 0; pass < 2; ++pass) {
        f4 c[16];
#pragma unroll
        for (int t = 0; t < 16; ++t) c[t] = (f4){0.f, 0.f, 0.f, 0.f};
        for (int s = 0; s < 10; ++s) {
            bh8 af = *(const bh8*)&big[(m0 + l16) * 328 + s * 32 + quad * 8];
#pragma unroll
            for (int h = 0; h < 2; ++h) {
                __syncthreads();
                for (int i = 0; i < 2; ++i) {
                    int u = i * 256 + tid;  // < 512
                    int row = u >> 2, off = u & 3;
                    *(bh8*)&slab[row * 40 + off * 8] =
                        *(const bh8*)&Wt[(pass * 256 + h * 128 + row) * MEM + s * 32 + off * 8];
                }
                __syncthreads();
#pragma unroll
                for (int t = 0; t < 8; ++t) {
                    bh8 bf = *(const bh8*)&slab[(t * 16 + l16) * 40 + quad * 8];
                    c[h*8+t] = __builtin_amdgcn_mfma_f32_16x16x32_bf16(af, bf, c[h*8+t], 0, 0, 0);
                }
            }
        }
#pragma unroll
        for (int t = 0; t < 16; ++t)
#pragma unroll
            for (int r = 0; r < 4; ++r)
                out3[(rowbase + m0 + quad*4 + r) * FEA + pass*256 + t*16 + l16] = c[t][r];
    }

    // ================= level 3: attend against sem_att =================
    __syncthreads();  // done reading att; reuse big[] for semT [512][40] (k<10 live, rest 0)
    for (int j = 0; j < 2; ++j) {
        int cc = tid * 2 + j;
#pragma unroll
        for (int k = 0; k < 40; ++k)
            big[cc * 40 + k] = (k < NCLS) ? f2b(sem_g[k * FEA + cc]) : (unsigned short)0;
    }
    __syncthreads();

    // logits2 = x @ sem_att^T via MFMA (classes on N, padded 10->16)
    f4 acc2 = (f4){0.f, 0.f, 0.f, 0.f};
    for (int s = 0; s < 16; ++s) {
        const float* ap = xrow + s * 32 + quad * 8;
        float4 a0 = *(const float4*)ap;
        float4 a1 = *(const float4*)(ap + 4);
        bh8 af;
        af[0]=(short)f2b(a0.x); af[1]=(short)f2b(a0.y); af[2]=(short)f2b(a0.z); af[3]=(short)f2b(a0.w);
        af[4]=(short)f2b(a1.x); af[5]=(short)f2b(a1.y); af[6]=(short)f2b(a1.z); af[7]=(short)f2b(a1.w);
        bh8 bf = (bh8){0,0,0,0,0,0,0,0};
        if (l16 < NCLS) {
            const float* sp = sem_g + l16 * FEA + s * 32 + quad * 8;
            float4 b0 = *(const float4*)sp;
            float4 b1 = *(const float4*)(sp + 4);
            bf[0]=(short)f2b(b0.x); bf[1]=(short)f2b(b0.y); bf[2]=(short)f2b(b0.z); bf[3]=(short)f2b(b0.w);
            bf[4]=(short)f2b(b1.x); bf[5]=(short)f2b(b1.y); bf[6]=(short)f2b(b1.z); bf[7]=(short)f2b(b1.w);
        }
        acc2 = __builtin_amdgcn_mfma_f32_16x16x32_bf16(af, bf, acc2, 0, 0, 0);
    }

    // masked softmax over 10 classes (classes live on l16 within each quad)
#pragma unroll
    for (int r = 0; r < 4; ++r) {
        float v  = acc2[r];
        float vm = (l16 < NCLS) ? v : -1e30f;
        for (int d = 1; d < 16; d <<= 1) vm = fmaxf(vm, __shfl_xor(vm, d));
        float e = (l16 < NCLS) ? __expf(v - vm) : 0.f;
        float ss = e;
        for (int d = 1; d < 16; d <<= 1) ss += __shfl_xor(ss, d);
        float p  = e / ss;
        float hs = (p > SHRK) ? ((p - SHRK) * p / (p - SHRK + EPSV)) : 0.f;
        float t2 = hs;
        for (int d = 1; d < 16; d <<= 1) t2 += __shfl_xor(t2, d);
        float a2 = hs / fmaxf(t2, EPSV);
        int row = m0 + quad * 4 + r;
        if (l16 < NCLS) out1[(rowbase + row) * 10 + l16] = a2;
        slab[row * 40 + l16] = f2b(a2);          // classes 10..15 are exactly 0
        slab[row * 40 + 16 + l16] = 0;           // zero k = 16..31 (pad for K=32)
    }
    __syncthreads();

    // output_sem = att2 @ sem_att via MFMA (K padded 10->32 with zeros)
    bh8 a2f = *(const bh8*)&slab[(m0 + l16) * 40 + quad * 8];
    f4 z4 = (f4){0.f, 0.f, 0.f, 0.f};
#pragma unroll
    for (int t = 0; t < 32; ++t) {
        bh8 bf = *(const bh8*)&big[(t * 16 + l16) * 40 + quad * 8];
        f4 o = __builtin_amdgcn_mfma_f32_16x16x32_bf16(a2f, bf, z4, 0, 0, 0);
#pragma unroll
        for (int r = 0; r < 4; ++r)
            out0[(rowbase + m0 + quad*4 + r) * FEA + t*16 + l16] = o[r];
    }
}

extern "C" void kernel_launch(void* const* d_in, const int* in_sizes, int n_in,
                              void* d_out, int out_size, void* d_ws, size_t ws_size,
                              hipStream_t stream) {
    const float* x  = (const float*)d_in[0];
    const float* W  = (const float*)d_in[1];
    const float* wp = (const float*)d_in[2];
    const float* bp = (const float*)d_in[3];
    const float* wi = (const float*)d_in[4];
    const float* bi = (const float*)d_in[5];
    float* out = (float*)d_out;
    const long o1 = (long)NR * FEA;           // output_sem size
    const long o2 = o1 + (long)NR * NCLS;     // + att2
    const long o3 = o2 + (long)NCLS * FEA;    // + sem_att

    unsigned short* Wb = (unsigned short*)d_ws;
    unsigned short* Wt = Wb + MEM * FEA;
    float* sem_ws = (float*)(Wt + MEM * FEA);

    cast_w<<<640, 256, 0, stream>>>(W, Wb, Wt);
    sem_kernel<<<8, 64, 0, stream>>>(W, wp, bp, wi, bi, sem_ws, out + o2);
    fused_kernel<<<2048, 256, 0, stream>>>(x, Wb, Wt, sem_ws,
                                           out, out + o1, out + o3);
}